// Round 3
// baseline (474.762 us; speedup 1.0000x reference)
//
#include <hip/hip_runtime.h>
#include <hip/hip_bf16.h>
#include <math.h>

// Router: logits = x@Wg ; softmax ; top-2 ; renormalized combine.
// T=65536, D=1024, E=64. Out flat fp32: [combine 2T][idx-as-float 2T][probs 64T].
//
// R9 = R8 (split-bf16 MFMA + flag-and-repair, HW-verified) minus its overheads:
//  - No LDS, no barriers: W (256 KB) is L1/L2-resident; every wave reads its
//    fragments straight from global (per-chunk working set 16 KB -> L1-hot).
//    Waves run fully independent -> natural latency hiding.
//  - Cast-based bf16 split (compiler emits v_cvt_pk_bf16_f32; ~3 VALU/elem vs
//    ~12 for the hand-rolled RNE) -- the R8 chunk loop was conversion-bound.
//  - TM=64 (1024 blocks, 4/CU) + launch_bounds(256,4): 2x waves/CU for TLP.
//  - Depth-2 x prefetch via two named register buffers (rule #20: static idx).
//  Accumulation chain per acc[et] identical to R8 (ch asc, s asc, hh/hl/lh),
//  so logits are bitwise-equal to the verified R8 -> same margin/repair behavior.

#define D_DIM 1024
#define E_DIM 64
#define TM    64               // tokens per block (4 waves x 16 tokens)
#define KC    64               // K per chunk
#define NCH   (D_DIM / KC)     // 16
#define TPB   256
#define MARGIN 1e-3f
#define WT_U4  16384           // uint4 granules in W planes (256 KB)

typedef float f32x4 __attribute__((ext_vector_type(4)));
typedef short s16x8 __attribute__((ext_vector_type(8)));

__device__ __forceinline__ ushort bf16u(float f) {
  union { __hip_bfloat16 b; ushort u; } cv;
  cv.b = __float2bfloat16(f);
  return cv.u;
}

// ---- W prep: Wg [1024][64] f32 -> wt bf16, layout [plane(hi,lo)][ch][e][g]
// (uint4 granules of 8 bf16, g = k-granule, linear -- no swizzle needed now
// that fragments are read from global, not LDS). Also zeroes the repair counter.
__global__ void wprep_kernel(const float* __restrict__ Wg, uint4* __restrict__ w4,
                             unsigned* __restrict__ ctr) {
  const int gi = blockIdx.x * blockDim.x + threadIdx.x;   // 0..8191
  if (gi == 0) ctr[0] = 0u;
  const int ch = gi >> 9;
  const int e  = (gi >> 3) & 63;
  const int g  = gi & 7;
  const int k0 = ch * KC + g * 8;
  unsigned hp[4], lp[4];
#pragma unroll
  for (int jj = 0; jj < 4; ++jj) {
    const float w0 = Wg[(k0 + 2 * jj    ) * E_DIM + e];
    const float w1 = Wg[(k0 + 2 * jj + 1) * E_DIM + e];
    const unsigned h0 = (unsigned)bf16u(w0) << 16;
    const unsigned h1 = (unsigned)bf16u(w1) << 16;
    const float l0 = w0 - __uint_as_float(h0);   // exact in fp32 (Sterbenz)
    const float l1 = w1 - __uint_as_float(h1);
    hp[jj] = (h1) | (h0 >> 16);
    lp[jj] = ((unsigned)bf16u(l1) << 16) | (unsigned)bf16u(l0);
  }
  w4[gi]        = make_uint4(hp[0], hp[1], hp[2], hp[3]);   // hi plane
  w4[8192 + gi] = make_uint4(lp[0], lp[1], lp[2], lp[3]);   // lo plane
}

struct Frag2 { s16x8 hi, lo; };

// 8 consecutive fp32 (k-run) -> hi/lo bf16x8 fragments, element j = k-order.
__device__ __forceinline__ Frag2 cvt8(const float4 a, const float4 b) {
  const float f[8] = {a.x, a.y, a.z, a.w, b.x, b.y, b.z, b.w};
  Frag2 r;
#pragma unroll
  for (int i = 0; i < 8; ++i) {
    const ushort h = bf16u(f[i]);
    r.hi[i] = (short)h;
    const float lf = f[i] - __uint_as_float((unsigned)h << 16);
    r.lo[i] = (short)bf16u(lf);
  }
  return r;
}

__global__ __launch_bounds__(TPB, 4) void router_mfma(
    const float* __restrict__ x, const uint4* __restrict__ wt,
    float* __restrict__ out, unsigned* __restrict__ ctr,
    unsigned* __restrict__ list, int rcap, int T)
{
  const int tid   = threadIdx.x;
  const int wid   = tid >> 6;
  const int lane  = tid & 63;
  const int c     = lane & 15;     // token col / expert row within 16-tile
  const int q     = lane >> 4;     // quarter -> k-granule
  const int tok   = blockIdx.x * TM + wid * 16 + c;

  f32x4 acc[4];                    // [etile]
#pragma unroll
  for (int et = 0; et < 4; ++et) acc[et] = (f32x4){0.f, 0.f, 0.f, 0.f};

  // x: lane reads floats [ch*64 + s*32 + q*8 .. +7] of row tok
  const float* __restrict__ xb = x + (size_t)tok * D_DIM + q * 8;
  // W: lane reads uint4 granule [plane][ch][et*16 + c][s*4 + q]
  const uint4* __restrict__ wl = wt + c * 8 + q;

  float4 xA[4], xB[4];             // chunk ch, ch+1 (depth-2 prefetch)
#pragma unroll
  for (int v = 0; v < 4; ++v) {
    const int s = v >> 1, h = v & 1;
    xA[v] = *(const float4*)(xb + s * 32 + h * 4);
    xB[v] = *(const float4*)(xb + KC + s * 32 + h * 4);
  }

  auto step = [&](float4 (&xr)[4], int ch) {
    // W fragments, s=0 half (L1/L2-hot)
    s16x8 a0h[4], a0l[4];
#pragma unroll
    for (int et = 0; et < 4; ++et) {
      a0h[et] = *(const s16x8*)(wl + (size_t)ch * 512 + et * 128);
      a0l[et] = *(const s16x8*)(wl + (size_t)ch * 512 + 8192 + et * 128);
    }
    const Frag2 b0 = cvt8(xr[0], xr[1]);
    const Frag2 b1 = cvt8(xr[2], xr[3]);
#pragma unroll
    for (int et = 0; et < 4; ++et) {
      f32x4 a = acc[et];
      a = __builtin_amdgcn_mfma_f32_16x16x32_bf16(a0h[et], b0.hi, a, 0, 0, 0);
      a = __builtin_amdgcn_mfma_f32_16x16x32_bf16(a0h[et], b0.lo, a, 0, 0, 0);
      a = __builtin_amdgcn_mfma_f32_16x16x32_bf16(a0l[et], b0.hi, a, 0, 0, 0);
      acc[et] = a;
    }
    // x prefetch, two chunks ahead (hides HBM latency under MFMA+cvt)
    if (ch + 2 < NCH) {
#pragma unroll
      for (int v = 0; v < 4; ++v) {
        const int s = v >> 1, h = v & 1;
        xr[v] = *(const float4*)(xb + (ch + 2) * KC + s * 32 + h * 4);
      }
    }
    // W fragments, s=1 half + MFMA
    s16x8 a1h[4], a1l[4];
#pragma unroll
    for (int et = 0; et < 4; ++et) {
      a1h[et] = *(const s16x8*)(wl + (size_t)ch * 512 + et * 128 + 4);
      a1l[et] = *(const s16x8*)(wl + (size_t)ch * 512 + 8192 + et * 128 + 4);
    }
#pragma unroll
    for (int et = 0; et < 4; ++et) {
      f32x4 a = acc[et];
      a = __builtin_amdgcn_mfma_f32_16x16x32_bf16(a1h[et], b1.hi, a, 0, 0, 0);
      a = __builtin_amdgcn_mfma_f32_16x16x32_bf16(a1h[et], b1.lo, a, 0, 0, 0);
      a = __builtin_amdgcn_mfma_f32_16x16x32_bf16(a1l[et], b1.hi, a, 0, 0, 0);
      acc[et] = a;
    }
  };

  for (int ch = 0; ch < NCH; ch += 2) {
    step(xA, ch);
    step(xB, ch + 1);
  }

  // ---- epilogue: token lives in lanes {c, c+16, c+32, c+48}; 16 logits/lane:
  // expert = et*16 + q*4 + r  (C/D layout: col=lane&15, row=(lane>>4)*4+reg)
  const size_t Ts = (size_t)T;
  float* const comb = out;
  float* const idxo = out + 2 * Ts;
  float* const prob = out + 4 * Ts;

  float v[16];
#pragma unroll
  for (int et = 0; et < 4; ++et)
#pragma unroll
    for (int r = 0; r < 4; ++r) v[et * 4 + r] = acc[et][r];

  // per-lane top-3 on raw logits (indices for top-2; ties -> lower index)
  float v1 = v[0], v2 = -INFINITY, v3 = -INFINITY;
  int   i1 = q * 4, i2 = 0;
#pragma unroll
  for (int et = 0; et < 4; ++et)
#pragma unroll
    for (int r = 0; r < 4; ++r) {
      if (et == 0 && r == 0) continue;
      const float p  = v[et * 4 + r];
      const int   ei = et * 16 + q * 4 + r;
      if (p > v1)      { v3 = v2; v2 = v1; i2 = i1; v1 = p; i1 = ei; }
      else if (p > v2) { v3 = v2; v2 = p;  i2 = ei; }
      else if (p > v3) { v3 = p; }
    }
  // merge top-3 across the 4 q-lanes (xor 16, 32); stable, symmetric
#pragma unroll
  for (int d = 16; d <= 32; d <<= 1) {
    const float ov1 = __shfl_xor(v1, d); const int oi1 = __shfl_xor(i1, d);
    const float ov2 = __shfl_xor(v2, d); const int oi2 = __shfl_xor(i2, d);
    const float ov3 = __shfl_xor(v3, d);
    const bool  ob1 = (ov1 > v1) || (ov1 == v1 && oi1 < i1);
    const float w1v = ob1 ? ov1 : v1;  const int w1i = ob1 ? oi1 : i1;
    const float l1v = ob1 ? v1  : ov1; const int l1i = ob1 ? i1  : oi1;
    const float w2v = ob1 ? ov2 : v2;  const int w2i = ob1 ? oi2 : i2;
    const float ls2 = ob1 ? v2  : ov2;               // loser-side 2nd (value only)
    const float ws3 = ob1 ? ov3 : v3;                 // winner-side 3rd (value only)
    const bool  b2  = (l1v > w2v) || (l1v == w2v && l1i < w2i);
    const float a2v = b2 ? l1v : w2v; const int a2i = b2 ? l1i : w2i;
    const float a3v = b2 ? fmaxf(w2v, ls2) : fmaxf(l1v, ws3);
    v1 = w1v; i1 = w1i; v2 = a2v; i2 = a2i; v3 = a3v;
  }

  // softmax: v1 is the exact max logit across all 64 experts
  float s = 0.f;
#pragma unroll
  for (int i = 0; i < 16; ++i) { v[i] = __expf(v[i] - v1); s += v[i]; }
  s += __shfl_xor(s, 16);
  s += __shfl_xor(s, 32);
  const float inv = 1.f / s;

#pragma unroll
  for (int et = 0; et < 4; ++et)
    *(float4*)&prob[(size_t)tok * E_DIM + et * 16 + q * 4] =
        make_float4(v[et * 4 + 0] * inv, v[et * 4 + 1] * inv,
                    v[et * 4 + 2] * inv, v[et * 4 + 3] * inv);

  if (q == 0) {
    if ((v1 - v2 < MARGIN) || (v2 - v3 < MARGIN)) {   // near-tie: queue exact repair
      const unsigned slot = atomicAdd(ctr, 1u);
      if ((int)slot < rcap) list[slot] = (unsigned)tok;
    }
    const float c1 = 1.f / (1.f + __expf(v2 - v1));   // == p1/(p1+p2)
    *(float2*)&comb[2 * (size_t)tok] = make_float2(c1, 1.f - c1);
    *(float2*)&idxo[2 * (size_t)tok] = make_float2((float)i1, (float)i2);
  }
}

// ---- exact repair: recompute flagged tokens' logits in fp64, overwrite outputs.
__global__ __launch_bounds__(256) void repair_kernel(
    const float* __restrict__ x, const float* __restrict__ Wg,
    float* __restrict__ out, const unsigned* __restrict__ ctr,
    const unsigned* __restrict__ list, int rcap, int T)
{
  __shared__ double part[4][E_DIM];
  const int tid = threadIdx.x;
  const int e   = tid & 63;
  const int s   = tid >> 6;
  const unsigned total = ctr[0];
  const unsigned n = total < (unsigned)rcap ? total : (unsigned)rcap;

  for (unsigned j = blockIdx.x; j < n; j += gridDim.x) {
    const int t = (int)list[j];
    const float* xr = x  + (size_t)t * D_DIM + s * 256;
    const float* wr = Wg + (size_t)(s * 256) * E_DIM + e;
    double a = 0.0;
#pragma unroll 8
    for (int d = 0; d < 256; ++d)
      a += (double)xr[d] * (double)wr[(size_t)d * E_DIM];
    part[s][e] = a;
    __syncthreads();
    if (tid < 64) {
      const float l = (float)(part[0][e] + part[1][e] + part[2][e] + part[3][e]);
      // wave-wide softmax over 64 experts
      float m = l;
#pragma unroll
      for (int d2 = 1; d2 < 64; d2 <<= 1) m = fmaxf(m, __shfl_xor(m, d2));
      const float p = expf(l - m);
      float ss = p;
#pragma unroll
      for (int d2 = 1; d2 < 64; d2 <<= 1) ss += __shfl_xor(ss, d2);
      out[4 * (size_t)T + (size_t)t * E_DIM + e] = p / ss;
      // wave-wide stable top-2 (ties -> lower index)
      float v1 = l, v2 = -INFINITY; int i1 = e, i2 = 0;
#pragma unroll
      for (int d2 = 1; d2 < 64; d2 <<= 1) {
        const float ov1 = __shfl_xor(v1, d2); const int oi1 = __shfl_xor(i1, d2);
        const float ov2 = __shfl_xor(v2, d2); const int oi2 = __shfl_xor(i2, d2);
        const bool  ob1 = (ov1 > v1) || (ov1 == v1 && oi1 < i1);
        const float w1v = ob1 ? ov1 : v1;  const int w1i = ob1 ? oi1 : i1;
        const float l1v = ob1 ? v1  : ov1; const int l1i = ob1 ? i1  : oi1;
        const float w2v = ob1 ? ov2 : v2;  const int w2i = ob1 ? oi2 : i2;
        const bool  b2  = (l1v > w2v) || (l1v == w2v && l1i < w2i);
        v1 = w1v; i1 = w1i;
        v2 = b2 ? l1v : w2v; i2 = b2 ? l1i : w2i;
      }
      if (e == 0) {
        const float c1 = 1.f / (1.f + expf(v2 - v1));
        out[2 * (size_t)t]     = c1;
        out[2 * (size_t)t + 1] = 1.f - c1;
        out[2 * (size_t)T + 2 * (size_t)t]     = (float)i1;
        out[2 * (size_t)T + 2 * (size_t)t + 1] = (float)i2;
      }
    }
    __syncthreads();
  }
}

extern "C" void kernel_launch(void* const* d_in, const int* in_sizes, int n_in,
                              void* d_out, int out_size, void* d_ws, size_t ws_size,
                              hipStream_t stream) {
  const float* x  = (const float*)d_in[0];
  const float* Wg = (const float*)d_in[1];
  float* out = (float*)d_out;
  uint4* wt  = (uint4*)d_ws;                       // 256 KB: split-bf16 W planes
  unsigned* ctr  = (unsigned*)d_ws + WT_U4 * 4;    // 1 counter after W planes
  unsigned* list = ctr + 1;                        // token ids to repair
  const int T = in_sizes[0] / D_DIM;               // 65536

  // clamp repair list to available workspace (expected ~900 entries)
  long avail = ((long)ws_size - (long)(WT_U4 * 16 + 4)) / 4;
  int rcap = avail < 0 ? 0 : (avail > 8192 ? 8192 : (int)avail);

  wprep_kernel<<<dim3(NCH * E_DIM * 8 / TPB), dim3(TPB), 0, stream>>>(Wg, wt, ctr);
  router_mfma<<<dim3(T / TM), dim3(TPB), 0, stream>>>(x, wt, out, ctr, list, rcap, T);
  repair_kernel<<<dim3(1024), dim3(256), 0, stream>>>(x, Wg, out, ctr, list, rcap, T);
}

// Round 4
// 429.077 us; speedup vs baseline: 1.1065x; 1.1065x over previous
//
#include <hip/hip_runtime.h>
#include <hip/hip_bf16.h>
#include <math.h>

// Router: logits = x@Wg ; softmax ; top-2 ; renormalized combine.
// T=65536, D=1024, E=64. Out flat fp32: [combine 2T][idx-as-float 2T][probs 64T].
//
// R10 = R8's verified LDS structure + R9's verified cheap pieces.
//   R9 post-mortem: global W-fragment reads -> compiler minimal-liveness schedule
//   (52 VGPR), ~12 dependent load-waits per chunk, x prefetch drained by vmcnt
//   ordering -> 193 us with all pipes <7% busy. W MUST come via LDS (ds_read is
//   lgkmcnt, leaves the x HBM prefetch in flight).
//   Kept from R8 (verified ~85-90 us): W global->reg->LDS dbuf, XOR-swizzled
//   granules (conflict-free ds_read_b128), W-prefetch issued BEFORE x-prefetch
//   so the ds_write's vmcnt wait never drains x.
//   New vs R8: cast-based bf16 split (v_cvt_pk path, ~4x less VALU in the chunk
//   loop); TM=64 -> 1024 blocks = 4 blocks/CU (2x TLP); x prefetch depth 2 via
//   named xA/xB (static indexing, rule #20); ah/al LDS reads interleaved to keep
//   VGPR liveness ~105 < 128 cap.
//   Per-acc accumulation order identical to R8/R9 -> same logits bitwise ->
//   same verified margin(1e-3) + fp64 flag-and-repair behavior (~900 tokens).

#define D_DIM 1024
#define E_DIM 64
#define TM    64               // tokens per block (4 waves x 16 tokens)
#define KC    64               // K per chunk
#define NCH   (D_DIM / KC)     // 16
#define TPB   256
#define MARGIN 1e-3f
#define WT_U4  16384           // uint4 granules in W planes (256 KB)

typedef float f32x4 __attribute__((ext_vector_type(4)));
typedef short s16x8 __attribute__((ext_vector_type(8)));

__device__ __forceinline__ ushort bf16u(float f) {
  union { __hip_bfloat16 b; ushort u; } cv;
  cv.b = __float2bfloat16(f);
  return cv.u;
}

// ---- W prep: Wg [1024][64] f32 -> wt bf16, layout [plane(hi,lo)][ch][e][g][j]
// (uint4 granules of 8 bf16). Granule slot g of row e holds source k-granule
// g^(e&7) of the chunk (XOR bank swizzle -> ds_read_b128 hits the 8-phase
// minimum, conflict-free). Also zeroes the repair counter.
__global__ void wprep_kernel(const float* __restrict__ Wg, uint4* __restrict__ w4,
                             unsigned* __restrict__ ctr) {
  const int gi = blockIdx.x * blockDim.x + threadIdx.x;   // 0..8191
  if (gi == 0) ctr[0] = 0u;
  const int ch = gi >> 9;
  const int e  = (gi >> 3) & 63;
  const int g  = gi & 7;
  const int k0 = ch * KC + (g ^ (e & 7)) * 8;
  unsigned hp[4], lp[4];
#pragma unroll
  for (int jj = 0; jj < 4; ++jj) {
    const float w0 = Wg[(k0 + 2 * jj    ) * E_DIM + e];
    const float w1 = Wg[(k0 + 2 * jj + 1) * E_DIM + e];
    const unsigned h0 = (unsigned)bf16u(w0) << 16;
    const unsigned h1 = (unsigned)bf16u(w1) << 16;
    const float l0 = w0 - __uint_as_float(h0);   // exact in fp32
    const float l1 = w1 - __uint_as_float(h1);
    hp[jj] = h1 | (h0 >> 16);
    lp[jj] = ((unsigned)bf16u(l1) << 16) | (unsigned)bf16u(l0);
  }
  w4[gi]        = make_uint4(hp[0], hp[1], hp[2], hp[3]);   // hi plane
  w4[8192 + gi] = make_uint4(lp[0], lp[1], lp[2], lp[3]);   // lo plane
}

struct Frag2 { s16x8 hi, lo; };

// 8 consecutive fp32 (k-run) -> hi/lo bf16x8 fragments, element j = k-order.
__device__ __forceinline__ Frag2 cvt8(const float4 a, const float4 b) {
  const float f[8] = {a.x, a.y, a.z, a.w, b.x, b.y, b.z, b.w};
  Frag2 r;
#pragma unroll
  for (int i = 0; i < 8; ++i) {
    const ushort h = bf16u(f[i]);
    r.hi[i] = (short)h;
    const float lf = f[i] - __uint_as_float((unsigned)h << 16);
    r.lo[i] = (short)bf16u(lf);
  }
  return r;
}

__global__ __launch_bounds__(TPB, 4) void router_mfma(
    const float* __restrict__ x, const uint4* __restrict__ wt,
    float* __restrict__ out, unsigned* __restrict__ ctr,
    unsigned* __restrict__ list, int rcap, int T)
{
  // per buf: [plane(0/1)*512 + e*8 + g] uint4 granules; 32 KB total
  __shared__ uint4 sw[2][1024];

  const int tid   = threadIdx.x;
  const int wid   = tid >> 6;
  const int lane  = tid & 63;
  const int c     = lane & 15;     // token col / expert row within 16-tile
  const int q     = lane >> 4;     // quarter -> k-granule
  const int tok   = blockIdx.x * TM + wid * 16 + c;

  f32x4 acc[4];                    // [etile]
#pragma unroll
  for (int et = 0; et < 4; ++et) acc[et] = (f32x4){0.f, 0.f, 0.f, 0.f};

  // x: lane reads floats [ch*64 + s*32 + q*8 .. +7] of row tok
  const float* __restrict__ xb = x + (size_t)tok * D_DIM + q * 8;

  uint4  wr[4];
  float4 xA[4], xB[4];             // chunks ch, ch+1 (depth-2 prefetch)

  // ---- prologue: W ch0 -> LDS buf0; x ch0,ch1 -> regs; W ch1 -> regs
#pragma unroll
  for (int i = 0; i < 4; ++i) wr[i] = wt[(i >> 1) * 8192 + (i & 1) * 256 + tid];
#pragma unroll
  for (int i = 0; i < 4; ++i) sw[0][(i >> 1) * 512 + (i & 1) * 256 + tid] = wr[i];
#pragma unroll
  for (int i = 0; i < 4; ++i) wr[i] = wt[(i >> 1) * 8192 + 512 + (i & 1) * 256 + tid];
#pragma unroll
  for (int v = 0; v < 4; ++v) {
    const int s = v >> 1, h = v & 1;
    xA[v] = *(const float4*)(xb + s * 32 + h * 4);
    xB[v] = *(const float4*)(xb + KC + s * 32 + h * 4);
  }
  __syncthreads();

  const int row0 = c * 64;                 // ushort offset of expert row c
  // swizzled granule (ushort offset) for the two k-halves
  const int g0 = ((0 + q) ^ (c & 7)) * 8;
  const int g1 = ((4 + q) ^ (c & 7)) * 8;

  auto stepf = [&](float4 (&xr)[4], int ch) {
    const int cur = ch & 1;
    if (ch + 1 < NCH) {                    // W regs(ch+1) -> other buffer
#pragma unroll
      for (int i = 0; i < 4; ++i)
        sw[cur ^ 1][(i >> 1) * 512 + (i & 1) * 256 + tid] = wr[i];
    }
    if (ch + 2 < NCH) {                    // prefetch W ch+2 (BEFORE x: vmcnt order)
#pragma unroll
      for (int i = 0; i < 4; ++i)
        wr[i] = wt[(i >> 1) * 8192 + (ch + 2) * 512 + (i & 1) * 256 + tid];
    }

    // convert this chunk's x (loaded 2 chunks ago -> latency long covered)
    const Frag2 b0 = cvt8(xr[0], xr[1]);
    const Frag2 b1 = cvt8(xr[2], xr[3]);

    if (ch + 2 < NCH) {                    // x prefetch, depth 2
#pragma unroll
      for (int v = 0; v < 4; ++v) {
        const int s = v >> 1, h = v & 1;
        xr[v] = *(const float4*)(xb + (ch + 2) * KC + s * 32 + h * 4);
      }
    }

    const ushort* bufh = (const ushort*)&sw[cur][0];
    const ushort* bufl = bufh + 4096;      // lo plane
#pragma unroll
    for (int s = 0; s < 2; ++s) {
      const int go = s ? g1 : g0;
      const Frag2& bs = s ? b1 : b0;
      s16x8 ah[4];
#pragma unroll
      for (int et = 0; et < 4; ++et)
        ah[et] = *(const s16x8*)(bufh + et * 1024 + row0 + go);
#pragma unroll
      for (int et = 0; et < 4; ++et) {
        f32x4 a = acc[et];
        a = __builtin_amdgcn_mfma_f32_16x16x32_bf16(ah[et], bs.hi, a, 0, 0, 0);
        a = __builtin_amdgcn_mfma_f32_16x16x32_bf16(ah[et], bs.lo, a, 0, 0, 0);
        acc[et] = a;
      }
      s16x8 al[4];
#pragma unroll
      for (int et = 0; et < 4; ++et)
        al[et] = *(const s16x8*)(bufl + et * 1024 + row0 + go);
#pragma unroll
      for (int et = 0; et < 4; ++et)
        acc[et] = __builtin_amdgcn_mfma_f32_16x16x32_bf16(al[et], bs.hi, acc[et], 0, 0, 0);
    }
    __syncthreads();
  };

  for (int ch = 0; ch < NCH; ch += 2) {
    stepf(xA, ch);
    stepf(xB, ch + 1);
  }

  // ---- epilogue (HW-verified in R8/R9): token lives in lanes {c,c+16,c+32,c+48};
  // 16 logits/lane: expert = et*16 + q*4 + r (C/D: col=lane&15, row=(lane>>4)*4+reg)
  const size_t Ts = (size_t)T;
  float* const comb = out;
  float* const idxo = out + 2 * Ts;
  float* const prob = out + 4 * Ts;

  float v[16];
#pragma unroll
  for (int et = 0; et < 4; ++et)
#pragma unroll
    for (int r = 0; r < 4; ++r) v[et * 4 + r] = acc[et][r];

  // per-lane top-3 on raw logits (indices for top-2; ties -> lower index)
  float v1 = v[0], v2 = -INFINITY, v3 = -INFINITY;
  int   i1 = q * 4, i2 = 0;
#pragma unroll
  for (int et = 0; et < 4; ++et)
#pragma unroll
    for (int r = 0; r < 4; ++r) {
      if (et == 0 && r == 0) continue;
      const float p  = v[et * 4 + r];
      const int   ei = et * 16 + q * 4 + r;
      if (p > v1)      { v3 = v2; v2 = v1; i2 = i1; v1 = p; i1 = ei; }
      else if (p > v2) { v3 = v2; v2 = p;  i2 = ei; }
      else if (p > v3) { v3 = p; }
    }
  // merge top-3 across the 4 q-lanes (xor 16, 32); stable, symmetric
#pragma unroll
  for (int d = 16; d <= 32; d <<= 1) {
    const float ov1 = __shfl_xor(v1, d); const int oi1 = __shfl_xor(i1, d);
    const float ov2 = __shfl_xor(v2, d); const int oi2 = __shfl_xor(i2, d);
    const float ov3 = __shfl_xor(v3, d);
    const bool  ob1 = (ov1 > v1) || (ov1 == v1 && oi1 < i1);
    const float w1v = ob1 ? ov1 : v1;  const int w1i = ob1 ? oi1 : i1;
    const float l1v = ob1 ? v1  : ov1; const int l1i = ob1 ? i1  : oi1;
    const float w2v = ob1 ? ov2 : v2;  const int w2i = ob1 ? oi2 : i2;
    const float ls2 = ob1 ? v2  : ov2;                // loser-side 2nd (value only)
    const float ws3 = ob1 ? ov3 : v3;                 // winner-side 3rd (value only)
    const bool  b2  = (l1v > w2v) || (l1v == w2v && l1i < w2i);
    const float a2v = b2 ? l1v : w2v; const int a2i = b2 ? l1i : w2i;
    const float a3v = b2 ? fmaxf(w2v, ls2) : fmaxf(l1v, ws3);
    v1 = w1v; i1 = w1i; v2 = a2v; i2 = a2i; v3 = a3v;
  }

  // softmax: v1 is the exact max logit across all 64 experts
  float s = 0.f;
#pragma unroll
  for (int i = 0; i < 16; ++i) { v[i] = __expf(v[i] - v1); s += v[i]; }
  s += __shfl_xor(s, 16);
  s += __shfl_xor(s, 32);
  const float inv = 1.f / s;

#pragma unroll
  for (int et = 0; et < 4; ++et)
    *(float4*)&prob[(size_t)tok * E_DIM + et * 16 + q * 4] =
        make_float4(v[et * 4 + 0] * inv, v[et * 4 + 1] * inv,
                    v[et * 4 + 2] * inv, v[et * 4 + 3] * inv);

  if (q == 0) {
    if ((v1 - v2 < MARGIN) || (v2 - v3 < MARGIN)) {   // near-tie: queue exact repair
      const unsigned slot = atomicAdd(ctr, 1u);
      if ((int)slot < rcap) list[slot] = (unsigned)tok;
    }
    const float c1 = 1.f / (1.f + __expf(v2 - v1));   // == p1/(p1+p2)
    *(float2*)&comb[2 * (size_t)tok] = make_float2(c1, 1.f - c1);
    *(float2*)&idxo[2 * (size_t)tok] = make_float2((float)i1, (float)i2);
  }
}

// ---- exact repair: recompute flagged tokens' logits in fp64, overwrite outputs.
__global__ __launch_bounds__(256) void repair_kernel(
    const float* __restrict__ x, const float* __restrict__ Wg,
    float* __restrict__ out, const unsigned* __restrict__ ctr,
    const unsigned* __restrict__ list, int rcap, int T)
{
  __shared__ double part[4][E_DIM];
  const int tid = threadIdx.x;
  const int e   = tid & 63;
  const int s   = tid >> 6;
  const unsigned total = ctr[0];
  const unsigned n = total < (unsigned)rcap ? total : (unsigned)rcap;

  for (unsigned j = blockIdx.x; j < n; j += gridDim.x) {
    const int t = (int)list[j];
    const float* xr = x  + (size_t)t * D_DIM + s * 256;
    const float* wr = Wg + (size_t)(s * 256) * E_DIM + e;
    double a = 0.0;
#pragma unroll 8
    for (int d = 0; d < 256; ++d)
      a += (double)xr[d] * (double)wr[(size_t)d * E_DIM];
    part[s][e] = a;
    __syncthreads();
    if (tid < 64) {
      const float l = (float)(part[0][e] + part[1][e] + part[2][e] + part[3][e]);
      // wave-wide softmax over 64 experts
      float m = l;
#pragma unroll
      for (int d2 = 1; d2 < 64; d2 <<= 1) m = fmaxf(m, __shfl_xor(m, d2));
      const float p = expf(l - m);
      float ss = p;
#pragma unroll
      for (int d2 = 1; d2 < 64; d2 <<= 1) ss += __shfl_xor(ss, d2);
      out[4 * (size_t)T + (size_t)t * E_DIM + e] = p / ss;
      // wave-wide stable top-2 (ties -> lower index)
      float v1 = l, v2 = -INFINITY; int i1 = e, i2 = 0;
#pragma unroll
      for (int d2 = 1; d2 < 64; d2 <<= 1) {
        const float ov1 = __shfl_xor(v1, d2); const int oi1 = __shfl_xor(i1, d2);
        const float ov2 = __shfl_xor(v2, d2); const int oi2 = __shfl_xor(i2, d2);
        const bool  ob1 = (ov1 > v1) || (ov1 == v1 && oi1 < i1);
        const float w1v = ob1 ? ov1 : v1;  const int w1i = ob1 ? oi1 : i1;
        const float l1v = ob1 ? v1  : ov1; const int l1i = ob1 ? i1  : oi1;
        const float w2v = ob1 ? ov2 : v2;  const int w2i = ob1 ? oi2 : i2;
        const bool  b2  = (l1v > w2v) || (l1v == w2v && l1i < w2i);
        v1 = w1v; i1 = w1i;
        v2 = b2 ? l1v : w2v; i2 = b2 ? l1i : w2i;
      }
      if (e == 0) {
        const float c1 = 1.f / (1.f + expf(v2 - v1));
        out[2 * (size_t)t]     = c1;
        out[2 * (size_t)t + 1] = 1.f - c1;
        out[2 * (size_t)T + 2 * (size_t)t]     = (float)i1;
        out[2 * (size_t)T + 2 * (size_t)t + 1] = (float)i2;
      }
    }
    __syncthreads();
  }
}

extern "C" void kernel_launch(void* const* d_in, const int* in_sizes, int n_in,
                              void* d_out, int out_size, void* d_ws, size_t ws_size,
                              hipStream_t stream) {
  const float* x  = (const float*)d_in[0];
  const float* Wg = (const float*)d_in[1];
  float* out = (float*)d_out;
  uint4* wt  = (uint4*)d_ws;                       // 256 KB: split-bf16 W planes
  unsigned* ctr  = (unsigned*)d_ws + WT_U4 * 4;    // 1 counter after W planes
  unsigned* list = ctr + 1;                        // token ids to repair
  const int T = in_sizes[0] / D_DIM;               // 65536

  // clamp repair list to available workspace (expected ~900 entries)
  long avail = ((long)ws_size - (long)(WT_U4 * 16 + 4)) / 4;
  int rcap = avail < 0 ? 0 : (avail > 8192 ? 8192 : (int)avail);

  wprep_kernel<<<dim3(NCH * E_DIM * 8 / TPB), dim3(TPB), 0, stream>>>(Wg, wt, ctr);
  router_mfma<<<dim3(T / TM), dim3(TPB), 0, stream>>>(x, wt, out, ctr, list, rcap, T);
  repair_kernel<<<dim3(1024), dim3(256), 0, stream>>>(x, Wg, out, ctr, list, rcap, T);
}

// Round 5
// 411.128 us; speedup vs baseline: 1.1548x; 1.0437x over previous
//
#include <hip/hip_runtime.h>
#include <hip/hip_bf16.h>
#include <math.h>

// Router: logits = x@Wg ; softmax ; top-2 ; renormalized combine.
// T=65536, D=1024, E=64. Out flat fp32: [combine 2T][idx-as-float 2T][probs 64T].
//
// R11: m97-style staging. R10 post-mortem: reg-roundtrip staging (global->VGPR->
// ds_write for W, x held 2 chunks in VGPR) => vmcnt entanglement + VGPR pressure;
// router ~147us vs 45us HBM floor. Fix per guide m151/m193: BOTH operands staged
// via __builtin_amdgcn_global_load_lds width=16 (no VGPR roundtrip, no ds_write).
//   BK=32, 32 chunks, 1 barrier/chunk: { stage(ch+1) async -> other buf;
//   ds_read+cvt+12 MFMA on ch; __syncthreads (drains vmcnt -> buf ready) }.
//   LDS 32 KB dbuf (x 2x8KB + W 2x8KB) -> 4 blocks/CU @ grid 1024, ~70 VGPR.
//   Conflict-freedom via SOURCE-side swizzle (gload_lds writes linearly, m104):
//   x: global granule g^(row&7) -> LDS dest is exactly linear (j*64+lane);
//      read slot (2q+h)^(c&7) -> 2-way (free).
//   W: swizzle baked into wprep layout slot = g^((e>>1)&3); read q^((c>>1)&3)
//      -> 2-way (free).
//   Per-acc MFMA chain (ch asc; hh,hl,lh) bitwise-identical to verified R8/R10
//   -> same logits -> same verified margin(1e-3) + fp64 flag-and-repair.

#define D_DIM 1024
#define E_DIM 64
#define TM    64               // tokens per block (4 waves x 16 tokens)
#define BK    32               // K per chunk
#define NCH   (D_DIM / BK)     // 32
#define TPB   256
#define MARGIN 1e-3f
#define WT_U4  16384           // uint4 granules in W planes (256 KB)

typedef float f32x4 __attribute__((ext_vector_type(4)));
typedef short s16x8 __attribute__((ext_vector_type(8)));

__device__ __forceinline__ ushort bf16u(float f) {
  union { __hip_bfloat16 b; ushort u; } cv;
  cv.b = __float2bfloat16(f);
  return cv.u;
}

// async global->LDS, 16 B per lane; LDS dest = wave-uniform base + lane*16
__device__ __forceinline__ void async_cp16(void* l, const void* g) {
  __builtin_amdgcn_global_load_lds(
      (const __attribute__((address_space(1))) void*)g,
      (__attribute__((address_space(3))) void*)l, 16, 0, 0);
}

// ---- W prep: Wg [1024][64] f32 -> wt bf16-split planes.
// Granule index: ((p*32 + ch)*64 + e)*4 + slot, each uint4 = 8 bf16 (k-order).
// Slot holds source k-granule g = slot ^ ((e>>1)&3)  (bank swizzle for the
// in-LDS fragment reads; staging copies this layout linearly).
__global__ void wprep_kernel(const float* __restrict__ Wg, uint4* __restrict__ w4,
                             unsigned* __restrict__ ctr) {
  const int gi = blockIdx.x * blockDim.x + threadIdx.x;   // 0..16383
  if (gi == 0) ctr[0] = 0u;
  const int p    = gi >> 13;
  const int ch   = (gi >> 8) & 31;
  const int e    = (gi >> 2) & 63;
  const int slot = gi & 3;
  const int g    = slot ^ ((e >> 1) & 3);
  const int k0   = ch * BK + g * 8;
  unsigned pk[4];
#pragma unroll
  for (int jj = 0; jj < 4; ++jj) {
    const float w0 = Wg[(k0 + 2 * jj    ) * E_DIM + e];
    const float w1 = Wg[(k0 + 2 * jj + 1) * E_DIM + e];
    if (p == 0) {
      pk[jj] = ((unsigned)bf16u(w1) << 16) | (unsigned)bf16u(w0);
    } else {
      const float l0 = w0 - __uint_as_float((unsigned)bf16u(w0) << 16);  // exact
      const float l1 = w1 - __uint_as_float((unsigned)bf16u(w1) << 16);
      pk[jj] = ((unsigned)bf16u(l1) << 16) | (unsigned)bf16u(l0);
    }
  }
  w4[gi] = make_uint4(pk[0], pk[1], pk[2], pk[3]);
}

struct Frag2 { s16x8 hi, lo; };

// 8 consecutive fp32 (k-run) -> hi/lo bf16x8 fragments, element j = k-order.
__device__ __forceinline__ Frag2 cvt8(const float4 a, const float4 b) {
  const float f[8] = {a.x, a.y, a.z, a.w, b.x, b.y, b.z, b.w};
  Frag2 r;
#pragma unroll
  for (int i = 0; i < 8; ++i) {
    const ushort h = bf16u(f[i]);
    r.hi[i] = (short)h;
    const float lf = f[i] - __uint_as_float((unsigned)h << 16);
    r.lo[i] = (short)bf16u(lf);
  }
  return r;
}

__global__ __launch_bounds__(TPB, 4) void router_mfma(
    const float* __restrict__ x, const uint4* __restrict__ wt,
    float* __restrict__ out, unsigned* __restrict__ ctr,
    unsigned* __restrict__ list, int rcap, int T)
{
  // x tile: [buf][trow*8 + slot] granules (64 rows x 8 granules = 32 fp32/row)
  // W tile: [buf][p*256 + e*4 + slot] granules (2 planes x 64 e x 4 = 32 bf16/row)
  __shared__ uint4 sx[2][512];
  __shared__ uint4 sw[2][512];

  const int tid  = threadIdx.x;
  const int wid  = tid >> 6;
  const int lane = tid & 63;
  const int c    = lane & 15;      // token col / expert row within 16-tile
  const int q    = lane >> 4;      // quarter -> k-granule
  const int trow = wid * 16 + c;   // block-local token row
  const int tok  = blockIdx.x * TM + trow;
  const size_t xbase = (size_t)blockIdx.x * TM * D_DIM;

  f32x4 acc[4];                    // [etile]
#pragma unroll
  for (int et = 0; et < 4; ++et) acc[et] = (f32x4){0.f, 0.f, 0.f, 0.f};

  const int j0 = wid * 2;          // this wave's two issue slots per operand

  auto stage = [&](int ch, int buf) {
    // x: 8 KB; issue j covers LDS granules [j*64, j*64+64) == rows j*8..j*8+7.
    // source granule XOR'd by row&7 -> LDS dest is exactly linear (j*64+lane).
#pragma unroll
    for (int i = 0; i < 2; ++i) {
      const int j    = j0 + i;
      const int rowr = j * 8 + (lane >> 3);
      const float* src = x + xbase + (size_t)rowr * D_DIM + ch * BK
                       + (((lane & 7) ^ (lane >> 3)) << 2);
      async_cp16(&sx[buf][j * 64], src);
    }
    // W: 8 KB; linear copy of the pre-swizzled wt layout for this chunk.
#pragma unroll
    for (int i = 0; i < 2; ++i) {
      const int j = j0 + i;
      const int G = j * 64 + lane;                 // 0..511
      const int p = G >> 8, r = G & 255;
      const uint4* src = wt + (size_t)(p * 32 + ch) * 256 + r;
      async_cp16(&sw[buf][j * 64], src);
    }
  };

  stage(0, 0);
  __syncthreads();                 // vmcnt(0) drain -> buf0 ready

  for (int ch = 0; ch < NCH; ++ch) {
    const int cur = ch & 1;
    if (ch + 1 < NCH) stage(ch + 1, cur ^ 1);

    // x fragment: 8 fp32, k = 8q..8q+7 of this chunk (2-way bank access, free)
    const float4* xb4 = (const float4*)&sx[cur][0];
    const int rb = trow * 8, key = c & 7;
    const float4 x0 = xb4[rb + ((2 * q + 0) ^ key)];
    const float4 x1 = xb4[rb + ((2 * q + 1) ^ key)];
    const Frag2 b = cvt8(x0, x1);

    // W fragments: hi/lo planes, 4 etiles (2-way bank access, free)
    const s16x8* wb = (const s16x8*)&sw[cur][0];
    const int slotr = q ^ ((c >> 1) & 3);
    s16x8 ah[4], al[4];
#pragma unroll
    for (int et = 0; et < 4; ++et) {
      const int e = et * 16 + c;
      ah[et] = wb[e * 4 + slotr];
      al[et] = wb[256 + e * 4 + slotr];
    }
#pragma unroll
    for (int et = 0; et < 4; ++et) {
      f32x4 a = acc[et];
      a = __builtin_amdgcn_mfma_f32_16x16x32_bf16(ah[et], b.hi, a, 0, 0, 0);
      a = __builtin_amdgcn_mfma_f32_16x16x32_bf16(ah[et], b.lo, a, 0, 0, 0);
      acc[et] = a;
    }
#pragma unroll
    for (int et = 0; et < 4; ++et)
      acc[et] = __builtin_amdgcn_mfma_f32_16x16x32_bf16(al[et], b.hi, acc[et], 0, 0, 0);

    __syncthreads();               // drains stage(ch+1); protects cur for reuse
  }

  // ---- epilogue (HW-verified R8/R9/R10): token in lanes {c,c+16,c+32,c+48};
  // 16 logits/lane: expert = et*16 + q*4 + r (C/D: col=lane&15, row=(lane>>4)*4+reg)
  const size_t Ts = (size_t)T;
  float* const comb = out;
  float* const idxo = out + 2 * Ts;
  float* const prob = out + 4 * Ts;

  float v[16];
#pragma unroll
  for (int et = 0; et < 4; ++et)
#pragma unroll
    for (int r = 0; r < 4; ++r) v[et * 4 + r] = acc[et][r];

  // per-lane top-3 on raw logits (indices for top-2; ties -> lower index)
  float v1 = v[0], v2 = -INFINITY, v3 = -INFINITY;
  int   i1 = q * 4, i2 = 0;
#pragma unroll
  for (int et = 0; et < 4; ++et)
#pragma unroll
    for (int r = 0; r < 4; ++r) {
      if (et == 0 && r == 0) continue;
      const float p  = v[et * 4 + r];
      const int   ei = et * 16 + q * 4 + r;
      if (p > v1)      { v3 = v2; v2 = v1; i2 = i1; v1 = p; i1 = ei; }
      else if (p > v2) { v3 = v2; v2 = p;  i2 = ei; }
      else if (p > v3) { v3 = p; }
    }
  // merge top-3 across the 4 q-lanes (xor 16, 32); stable, symmetric
#pragma unroll
  for (int d = 16; d <= 32; d <<= 1) {
    const float ov1 = __shfl_xor(v1, d); const int oi1 = __shfl_xor(i1, d);
    const float ov2 = __shfl_xor(v2, d); const int oi2 = __shfl_xor(i2, d);
    const float ov3 = __shfl_xor(v3, d);
    const bool  ob1 = (ov1 > v1) || (ov1 == v1 && oi1 < i1);
    const float w1v = ob1 ? ov1 : v1;  const int w1i = ob1 ? oi1 : i1;
    const float l1v = ob1 ? v1  : ov1; const int l1i = ob1 ? i1  : oi1;
    const float w2v = ob1 ? ov2 : v2;  const int w2i = ob1 ? oi2 : i2;
    const float ls2 = ob1 ? v2  : ov2;                // loser-side 2nd (value only)
    const float ws3 = ob1 ? ov3 : v3;                 // winner-side 3rd (value only)
    const bool  b2  = (l1v > w2v) || (l1v == w2v && l1i < w2i);
    const float a2v = b2 ? l1v : w2v; const int a2i = b2 ? l1i : w2i;
    const float a3v = b2 ? fmaxf(w2v, ls2) : fmaxf(l1v, ws3);
    v1 = w1v; i1 = w1i; v2 = a2v; i2 = a2i; v3 = a3v;
  }

  // softmax: v1 is the exact max logit across all 64 experts
  float s = 0.f;
#pragma unroll
  for (int i = 0; i < 16; ++i) { v[i] = __expf(v[i] - v1); s += v[i]; }
  s += __shfl_xor(s, 16);
  s += __shfl_xor(s, 32);
  const float inv = 1.f / s;

#pragma unroll
  for (int et = 0; et < 4; ++et)
    *(float4*)&prob[(size_t)tok * E_DIM + et * 16 + q * 4] =
        make_float4(v[et * 4 + 0] * inv, v[et * 4 + 1] * inv,
                    v[et * 4 + 2] * inv, v[et * 4 + 3] * inv);

  if (q == 0) {
    if ((v1 - v2 < MARGIN) || (v2 - v3 < MARGIN)) {   // near-tie: queue exact repair
      const unsigned slot = atomicAdd(ctr, 1u);
      if ((int)slot < rcap) list[slot] = (unsigned)tok;
    }
    const float c1 = 1.f / (1.f + __expf(v2 - v1));   // == p1/(p1+p2)
    *(float2*)&comb[2 * (size_t)tok] = make_float2(c1, 1.f - c1);
    *(float2*)&idxo[2 * (size_t)tok] = make_float2((float)i1, (float)i2);
  }
}

// ---- exact repair: recompute flagged tokens' logits in fp64, overwrite outputs.
__global__ __launch_bounds__(256) void repair_kernel(
    const float* __restrict__ x, const float* __restrict__ Wg,
    float* __restrict__ out, const unsigned* __restrict__ ctr,
    const unsigned* __restrict__ list, int rcap, int T)
{
  __shared__ double part[4][E_DIM];
  const int tid = threadIdx.x;
  const int e   = tid & 63;
  const int s   = tid >> 6;
  const unsigned total = ctr[0];
  const unsigned n = total < (unsigned)rcap ? total : (unsigned)rcap;

  for (unsigned j = blockIdx.x; j < n; j += gridDim.x) {
    const int t = (int)list[j];
    const float* xr = x  + (size_t)t * D_DIM + s * 256;
    const float* wr = Wg + (size_t)(s * 256) * E_DIM + e;
    double a = 0.0;
#pragma unroll 8
    for (int d = 0; d < 256; ++d)
      a += (double)xr[d] * (double)wr[(size_t)d * E_DIM];
    part[s][e] = a;
    __syncthreads();
    if (tid < 64) {
      const float l = (float)(part[0][e] + part[1][e] + part[2][e] + part[3][e]);
      // wave-wide softmax over 64 experts
      float m = l;
#pragma unroll
      for (int d2 = 1; d2 < 64; d2 <<= 1) m = fmaxf(m, __shfl_xor(m, d2));
      const float p = expf(l - m);
      float ss = p;
#pragma unroll
      for (int d2 = 1; d2 < 64; d2 <<= 1) ss += __shfl_xor(ss, d2);
      out[4 * (size_t)T + (size_t)t * E_DIM + e] = p / ss;
      // wave-wide stable top-2 (ties -> lower index)
      float v1 = l, v2 = -INFINITY; int i1 = e, i2 = 0;
#pragma unroll
      for (int d2 = 1; d2 < 64; d2 <<= 1) {
        const float ov1 = __shfl_xor(v1, d2); const int oi1 = __shfl_xor(i1, d2);
        const float ov2 = __shfl_xor(v2, d2); const int oi2 = __shfl_xor(i2, d2);
        const bool  ob1 = (ov1 > v1) || (ov1 == v1 && oi1 < i1);
        const float w1v = ob1 ? ov1 : v1;  const int w1i = ob1 ? oi1 : i1;
        const float l1v = ob1 ? v1  : ov1; const int l1i = ob1 ? i1  : oi1;
        const float w2v = ob1 ? ov2 : v2;  const int w2i = ob1 ? oi2 : i2;
        const bool  b2  = (l1v > w2v) || (l1v == w2v && l1i < w2i);
        v1 = w1v; i1 = w1i;
        v2 = b2 ? l1v : w2v; i2 = b2 ? l1i : w2i;
      }
      if (e == 0) {
        const float c1 = 1.f / (1.f + expf(v2 - v1));
        out[2 * (size_t)t]     = c1;
        out[2 * (size_t)t + 1] = 1.f - c1;
        out[2 * (size_t)T + 2 * (size_t)t]     = (float)i1;
        out[2 * (size_t)T + 2 * (size_t)t + 1] = (float)i2;
      }
    }
    __syncthreads();
  }
}

extern "C" void kernel_launch(void* const* d_in, const int* in_sizes, int n_in,
                              void* d_out, int out_size, void* d_ws, size_t ws_size,
                              hipStream_t stream) {
  const float* x  = (const float*)d_in[0];
  const float* Wg = (const float*)d_in[1];
  float* out = (float*)d_out;
  uint4* wt  = (uint4*)d_ws;                       // 256 KB: split-bf16 W planes
  unsigned* ctr  = (unsigned*)d_ws + WT_U4 * 4;    // 1 counter after W planes
  unsigned* list = ctr + 1;                        // token ids to repair
  const int T = in_sizes[0] / D_DIM;               // 65536

  // clamp repair list to available workspace (expected ~900 entries)
  long avail = ((long)ws_size - (long)(WT_U4 * 16 + 4)) / 4;
  int rcap = avail < 0 ? 0 : (avail > 8192 ? 8192 : (int)avail);

  wprep_kernel<<<dim3(WT_U4 / TPB), dim3(TPB), 0, stream>>>(Wg, wt, ctr);
  router_mfma<<<dim3(T / TM), dim3(TPB), 0, stream>>>(x, wt, out, ctr, list, rcap, T);
  repair_kernel<<<dim3(1024), dim3(256), 0, stream>>>(x, Wg, out, ctr, list, rcap, T);
}

// Round 6
// 391.953 us; speedup vs baseline: 1.2113x; 1.0489x over previous
//
#include <hip/hip_runtime.h>
#include <hip/hip_bf16.h>
#include <math.h>

// Router: logits = x@Wg ; softmax ; top-2 ; renormalized combine.
// T=65536, D=1024, E=64. Out flat fp32: [combine 2T][idx-as-float 2T][probs 64T].
//
// R12 = R11 (passed, ~130us) restructured to kill per-chunk barrier-drain.
//   R11 post-mortem: 32 chunks x {stage, 12-MFMA body (~230cy), syncthreads
//   with vmcnt(0) drain} -- body << HBM latency, so every barrier exposed
//   ~500cy of raw latency. Pipes all idle (DS 26us, MFMA 10us vs 130us).
//   Fix:
//   - BK=128 (8 chunks): body = 48 MFMA + 32 ds_read + 4 cvt8 ~ 1000cy >
//     HBM latency -> loads issued at chunk start complete before the barrier.
//   - x NEVER in LDS (zero reuse): global->reg in B-fragment layout, prefetched
//     one full chunk ahead via named xA/xB (static indexing, rule #20).
//   - W: 32KB/chunk dbuf via global_load_lds w=16 (64KB LDS), same pre-swizzled
//     wprep layout as R11 (slot = g ^ ((e>>1)&3) -> 2-way LDS reads, free).
//   - 512-thread blocks (8 waves, TM=128), grid 512 = 2 blocks/CU,
//     launch_bounds(512,4) -> 128-VGPR cap (est ~120 live).
//   Per-acc MFMA order (ch32 ascending; hh,hl,lh) bitwise-identical to the
//   verified R11 -> same logits -> same margin(1e-3)+fp64 flag-and-repair.

#define D_DIM 1024
#define E_DIM 64
#define TM    128              // tokens per block (8 waves x 16 tokens)
#define BK    128              // K per chunk
#define NCHB  (D_DIM / BK)     // 8
#define TPB   512
#define MARGIN 1e-3f
#define WT_U4  16384           // uint4 granules in W planes (256 KB)

typedef float f32x4 __attribute__((ext_vector_type(4)));
typedef short s16x8 __attribute__((ext_vector_type(8)));

__device__ __forceinline__ ushort bf16u(float f) {
  union { __hip_bfloat16 b; ushort u; } cv;
  cv.b = __float2bfloat16(f);
  return cv.u;
}

// async global->LDS, 16 B per lane; LDS dest = wave-uniform base + lane*16
__device__ __forceinline__ void async_cp16(void* l, const void* g) {
  __builtin_amdgcn_global_load_lds(
      (const __attribute__((address_space(1))) void*)g,
      (__attribute__((address_space(3))) void*)l, 16, 0, 0);
}

// ---- W prep (unchanged from R11, HW-verified): Wg [1024][64] f32 -> split-bf16
// planes. Granule index ((p*32 + ch32)*64 + e)*4 + slot, uint4 = 8 bf16 k-order.
// Slot holds source k-granule g = slot ^ ((e>>1)&3) (bank swizzle for fragment
// reads; staging copies the layout linearly). Also zeroes the repair counter.
__global__ void wprep_kernel(const float* __restrict__ Wg, uint4* __restrict__ w4,
                             unsigned* __restrict__ ctr) {
  const int gi = blockIdx.x * blockDim.x + threadIdx.x;   // 0..16383
  if (gi == 0) ctr[0] = 0u;
  const int p    = gi >> 13;
  const int ch   = (gi >> 8) & 31;
  const int e    = (gi >> 2) & 63;
  const int slot = gi & 3;
  const int g    = slot ^ ((e >> 1) & 3);
  const int k0   = ch * 32 + g * 8;
  unsigned pk[4];
#pragma unroll
  for (int jj = 0; jj < 4; ++jj) {
    const float w0 = Wg[(k0 + 2 * jj    ) * E_DIM + e];
    const float w1 = Wg[(k0 + 2 * jj + 1) * E_DIM + e];
    if (p == 0) {
      pk[jj] = ((unsigned)bf16u(w1) << 16) | (unsigned)bf16u(w0);
    } else {
      const float l0 = w0 - __uint_as_float((unsigned)bf16u(w0) << 16);  // exact
      const float l1 = w1 - __uint_as_float((unsigned)bf16u(w1) << 16);
      pk[jj] = ((unsigned)bf16u(l1) << 16) | (unsigned)bf16u(l0);
    }
  }
  w4[gi] = make_uint4(pk[0], pk[1], pk[2], pk[3]);
}

struct Frag2 { s16x8 hi, lo; };

// 8 consecutive fp32 (k-run) -> hi/lo bf16x8 fragments, element j = k-order.
__device__ __forceinline__ Frag2 cvt8(const float4 a, const float4 b) {
  const float f[8] = {a.x, a.y, a.z, a.w, b.x, b.y, b.z, b.w};
  Frag2 r;
#pragma unroll
  for (int i = 0; i < 8; ++i) {
    const ushort h = bf16u(f[i]);
    r.hi[i] = (short)h;
    const float lf = f[i] - __uint_as_float((unsigned)h << 16);
    r.lo[i] = (short)bf16u(lf);
  }
  return r;
}

__global__ __launch_bounds__(TPB, 4) void router_mfma(
    const float* __restrict__ x, const uint4* __restrict__ wt,
    float* __restrict__ out, unsigned* __restrict__ ctr,
    unsigned* __restrict__ list, int rcap, int T)
{
  // W tile per chunk: 4 sub-chunks x [p*256 + e*4 + slot] granules = 2048 u4 = 32 KB
  __shared__ uint4 swW[2][2048];

  const int tid  = threadIdx.x;
  const int wid  = tid >> 6;       // 0..7
  const int lane = tid & 63;
  const int c    = lane & 15;      // token col / expert row within 16-tile
  const int q    = lane >> 4;      // quarter -> k-granule
  const int tok  = blockIdx.x * TM + wid * 16 + c;

  f32x4 acc[4];                    // [etile]
#pragma unroll
  for (int et = 0; et < 4; ++et) acc[et] = (f32x4){0.f, 0.f, 0.f, 0.f};

  // x: lane reads floats [ch*128 + sub*32 + q*8 .. +7] of row tok
  const float* __restrict__ xb = x + (size_t)tok * D_DIM + q * 8;

  // W staging geometry: round r covers LDS granules [r*512+wid*64, +64);
  // wave-uniform p = wid>>2 (hi/lo plane), rr = (wid&3)*64+lane within plane.
  const int pw = wid >> 2;
  const int rr = (wid & 3) * 64 + lane;

  auto stageW = [&](int ch, int buf) {
#pragma unroll
    for (int r = 0; r < 4; ++r)
      async_cp16(&swW[buf][r * 512 + wid * 64],
                 wt + (size_t)(pw * 32 + ch * 4 + r) * 256 + rr);
  };

  auto loadx = [&](float4 (&xr)[8], int ch) {
#pragma unroll
    for (int sub = 0; sub < 4; ++sub)
#pragma unroll
      for (int h = 0; h < 2; ++h)
        xr[sub * 2 + h] = *(const float4*)(xb + ch * BK + sub * 32 + h * 4);
  };

  const int slotr = q ^ ((c >> 1) & 3);

  auto compute = [&](const float4 (&xr)[8], int buf) {
#pragma unroll
    for (int sub = 0; sub < 4; ++sub) {
      const Frag2 b = cvt8(xr[sub * 2], xr[sub * 2 + 1]);
      const s16x8* wb = (const s16x8*)&swW[buf][sub * 512];
      s16x8 ah[4], al[4];
#pragma unroll
      for (int et = 0; et < 4; ++et) {
        const int e = et * 16 + c;
        ah[et] = wb[e * 4 + slotr];
        al[et] = wb[256 + e * 4 + slotr];
      }
#pragma unroll
      for (int et = 0; et < 4; ++et) {
        f32x4 a = acc[et];
        a = __builtin_amdgcn_mfma_f32_16x16x32_bf16(ah[et], b.hi, a, 0, 0, 0);
        a = __builtin_amdgcn_mfma_f32_16x16x32_bf16(ah[et], b.lo, a, 0, 0, 0);
        acc[et] = a;
      }
#pragma unroll
      for (int et = 0; et < 4; ++et)
        acc[et] = __builtin_amdgcn_mfma_f32_16x16x32_bf16(al[et], b.hi, acc[et], 0, 0, 0);
    }
  };

  float4 xA[8], xB[8];

  // ---- prologue: W ch0 -> LDS buf0 (async); x ch0 -> regs; barrier drains both
  stageW(0, 0);
  loadx(xA, 0);
  __syncthreads();

  for (int cp = 0; cp < NCHB; cp += 2) {
    // chunk cp (even): W in buf0
    if (cp + 1 < NCHB) { stageW(cp + 1, 1); loadx(xB, cp + 1); }
    compute(xA, 0);
    __syncthreads();
    // chunk cp+1 (odd): W in buf1
    if (cp + 2 < NCHB) { stageW(cp + 2, 0); loadx(xA, cp + 2); }
    compute(xB, 1);
    __syncthreads();
  }

  // ---- epilogue (HW-verified R8..R11): token in lanes {c,c+16,c+32,c+48};
  // 16 logits/lane: expert = et*16 + q*4 + r (C/D: col=lane&15, row=(lane>>4)*4+reg)
  const size_t Ts = (size_t)T;
  float* const comb = out;
  float* const idxo = out + 2 * Ts;
  float* const prob = out + 4 * Ts;

  float v[16];
#pragma unroll
  for (int et = 0; et < 4; ++et)
#pragma unroll
    for (int r = 0; r < 4; ++r) v[et * 4 + r] = acc[et][r];

  // per-lane top-3 on raw logits (indices for top-2; ties -> lower index)
  float v1 = v[0], v2 = -INFINITY, v3 = -INFINITY;
  int   i1 = q * 4, i2 = 0;
#pragma unroll
  for (int et = 0; et < 4; ++et)
#pragma unroll
    for (int r = 0; r < 4; ++r) {
      if (et == 0 && r == 0) continue;
      const float p  = v[et * 4 + r];
      const int   ei = et * 16 + q * 4 + r;
      if (p > v1)      { v3 = v2; v2 = v1; i2 = i1; v1 = p; i1 = ei; }
      else if (p > v2) { v3 = v2; v2 = p;  i2 = ei; }
      else if (p > v3) { v3 = p; }
    }
  // merge top-3 across the 4 q-lanes (xor 16, 32); stable, symmetric
#pragma unroll
  for (int d = 16; d <= 32; d <<= 1) {
    const float ov1 = __shfl_xor(v1, d); const int oi1 = __shfl_xor(i1, d);
    const float ov2 = __shfl_xor(v2, d); const int oi2 = __shfl_xor(i2, d);
    const float ov3 = __shfl_xor(v3, d);
    const bool  ob1 = (ov1 > v1) || (ov1 == v1 && oi1 < i1);
    const float w1v = ob1 ? ov1 : v1;  const int w1i = ob1 ? oi1 : i1;
    const float l1v = ob1 ? v1  : ov1; const int l1i = ob1 ? i1  : oi1;
    const float w2v = ob1 ? ov2 : v2;  const int w2i = ob1 ? oi2 : i2;
    const float ls2 = ob1 ? v2  : ov2;                // loser-side 2nd (value only)
    const float ws3 = ob1 ? ov3 : v3;                 // winner-side 3rd (value only)
    const bool  b2  = (l1v > w2v) || (l1v == w2v && l1i < w2i);
    const float a2v = b2 ? l1v : w2v; const int a2i = b2 ? l1i : w2i;
    const float a3v = b2 ? fmaxf(w2v, ls2) : fmaxf(l1v, ws3);
    v1 = w1v; i1 = w1i; v2 = a2v; i2 = a2i; v3 = a3v;
  }

  // softmax: v1 is the exact max logit across all 64 experts
  float s = 0.f;
#pragma unroll
  for (int i = 0; i < 16; ++i) { v[i] = __expf(v[i] - v1); s += v[i]; }
  s += __shfl_xor(s, 16);
  s += __shfl_xor(s, 32);
  const float inv = 1.f / s;

#pragma unroll
  for (int et = 0; et < 4; ++et)
    *(float4*)&prob[(size_t)tok * E_DIM + et * 16 + q * 4] =
        make_float4(v[et * 4 + 0] * inv, v[et * 4 + 1] * inv,
                    v[et * 4 + 2] * inv, v[et * 4 + 3] * inv);

  if (q == 0) {
    if ((v1 - v2 < MARGIN) || (v2 - v3 < MARGIN)) {   // near-tie: queue exact repair
      const unsigned slot = atomicAdd(ctr, 1u);
      if ((int)slot < rcap) list[slot] = (unsigned)tok;
    }
    const float c1 = 1.f / (1.f + __expf(v2 - v1));   // == p1/(p1+p2)
    *(float2*)&comb[2 * (size_t)tok] = make_float2(c1, 1.f - c1);
    *(float2*)&idxo[2 * (size_t)tok] = make_float2((float)i1, (float)i2);
  }
}

// ---- exact repair: recompute flagged tokens' logits in fp64, overwrite outputs.
__global__ __launch_bounds__(256) void repair_kernel(
    const float* __restrict__ x, const float* __restrict__ Wg,
    float* __restrict__ out, const unsigned* __restrict__ ctr,
    const unsigned* __restrict__ list, int rcap, int T)
{
  __shared__ double part[4][E_DIM];
  const int tid = threadIdx.x;
  const int e   = tid & 63;
  const int s   = tid >> 6;
  const unsigned total = ctr[0];
  const unsigned n = total < (unsigned)rcap ? total : (unsigned)rcap;

  for (unsigned j = blockIdx.x; j < n; j += gridDim.x) {
    const int t = (int)list[j];
    const float* xr = x  + (size_t)t * D_DIM + s * 256;
    const float* wr = Wg + (size_t)(s * 256) * E_DIM + e;
    double a = 0.0;
#pragma unroll 8
    for (int d = 0; d < 256; ++d)
      a += (double)xr[d] * (double)wr[(size_t)d * E_DIM];
    part[s][e] = a;
    __syncthreads();
    if (tid < 64) {
      const float l = (float)(part[0][e] + part[1][e] + part[2][e] + part[3][e]);
      // wave-wide softmax over 64 experts
      float m = l;
#pragma unroll
      for (int d2 = 1; d2 < 64; d2 <<= 1) m = fmaxf(m, __shfl_xor(m, d2));
      const float p = expf(l - m);
      float ss = p;
#pragma unroll
      for (int d2 = 1; d2 < 64; d2 <<= 1) ss += __shfl_xor(ss, d2);
      out[4 * (size_t)T + (size_t)t * E_DIM + e] = p / ss;
      // wave-wide stable top-2 (ties -> lower index)
      float v1 = l, v2 = -INFINITY; int i1 = e, i2 = 0;
#pragma unroll
      for (int d2 = 1; d2 < 64; d2 <<= 1) {
        const float ov1 = __shfl_xor(v1, d2); const int oi1 = __shfl_xor(i1, d2);
        const float ov2 = __shfl_xor(v2, d2); const int oi2 = __shfl_xor(i2, d2);
        const bool  ob1 = (ov1 > v1) || (ov1 == v1 && oi1 < i1);
        const float w1v = ob1 ? ov1 : v1;  const int w1i = ob1 ? oi1 : i1;
        const float l1v = ob1 ? v1  : ov1; const int l1i = ob1 ? i1  : oi1;
        const float w2v = ob1 ? ov2 : v2;  const int w2i = ob1 ? oi2 : i2;
        const bool  b2  = (l1v > w2v) || (l1v == w2v && l1i < w2i);
        v1 = w1v; i1 = w1i;
        v2 = b2 ? l1v : w2v; i2 = b2 ? l1i : w2i;
      }
      if (e == 0) {
        const float c1 = 1.f / (1.f + expf(v2 - v1));
        out[2 * (size_t)t]     = c1;
        out[2 * (size_t)t + 1] = 1.f - c1;
        out[2 * (size_t)T + 2 * (size_t)t]     = (float)i1;
        out[2 * (size_t)T + 2 * (size_t)t + 1] = (float)i2;
      }
    }
    __syncthreads();
  }
}

extern "C" void kernel_launch(void* const* d_in, const int* in_sizes, int n_in,
                              void* d_out, int out_size, void* d_ws, size_t ws_size,
                              hipStream_t stream) {
  const float* x  = (const float*)d_in[0];
  const float* Wg = (const float*)d_in[1];
  float* out = (float*)d_out;
  uint4* wt  = (uint4*)d_ws;                       // 256 KB: split-bf16 W planes
  unsigned* ctr  = (unsigned*)d_ws + WT_U4 * 4;    // 1 counter after W planes
  unsigned* list = ctr + 1;                        // token ids to repair
  const int T = in_sizes[0] / D_DIM;               // 65536

  // clamp repair list to available workspace (expected ~900 entries)
  long avail = ((long)ws_size - (long)(WT_U4 * 16 + 4)) / 4;
  int rcap = avail < 0 ? 0 : (avail > 8192 ? 8192 : (int)avail);

  wprep_kernel<<<dim3(WT_U4 / 256), dim3(256), 0, stream>>>(Wg, wt, ctr);
  router_mfma<<<dim3(T / TM), dim3(TPB), 0, stream>>>(x, wt, out, ctr, list, rcap, T);
  repair_kernel<<<dim3(1024), dim3(256), 0, stream>>>(x, Wg, out, ctr, list, rcap, T);
}